// Round 4
// baseline (142.498 us; speedup 1.0000x reference)
//
#include <hip/hip_runtime.h>

#define GYD 1024
#define GXD 1024
#define NUM_BEV 8

__device__ __forceinline__ float rdlanef(float x, int l) {
    return __int_as_float(__builtin_amdgcn_readlane(__float_as_int(x), l));
}
// DPP building block: returns src shifted per CTRL; lanes with no source (or
// outside ROWMASK) receive `oldv`.
template <int CTRL, int ROWMASK>
__device__ __forceinline__ float dppf(float x, float oldv) {
    return __int_as_float(__builtin_amdgcn_update_dpp(
        __float_as_int(oldv), __float_as_int(x), CTRL, ROWMASK, 0xF, false));
}
// 32-lane-group reductions, pure VALU (no LDS pipe). Result in lanes 31 and 63.
__device__ __forceinline__ float dsum32(float x) {
    x += dppf<0x111, 0xF>(x, 0.f);   // row_shr:1
    x += dppf<0x112, 0xF>(x, 0.f);   // row_shr:2
    x += dppf<0x114, 0xF>(x, 0.f);   // row_shr:4
    x += dppf<0x118, 0xF>(x, 0.f);   // row_shr:8
    x += dppf<0x142, 0xA>(x, 0.f);   // row_bcast:15 into odd rows
    return x;
}
__device__ __forceinline__ float dmax32(float x) {
    x = fmaxf(x, dppf<0x111, 0xF>(x, x));
    x = fmaxf(x, dppf<0x112, 0xF>(x, x));
    x = fmaxf(x, dppf<0x114, 0xF>(x, x));
    x = fmaxf(x, dppf<0x118, 0xF>(x, x));
    x = fmaxf(x, dppf<0x142, 0xA>(x, x));
    return x;
}
__device__ __forceinline__ float dmin32(float x) {
    x = fminf(x, dppf<0x111, 0xF>(x, x));
    x = fminf(x, dppf<0x112, 0xF>(x, x));
    x = fminf(x, dppf<0x114, 0xF>(x, x));
    x = fminf(x, dppf<0x118, 0xF>(x, x));
    x = fminf(x, dppf<0x142, 0xA>(x, x));
    return x;
}

// TWO pillars per wave (lanes 0-31 / 32-63), 4 waves per block, NO LDS, no barrier.
__global__ __launch_bounds__(256) void pillar_kernel(
    const float4* __restrict__ vf,       // N*32 points (x,y,z,intensity)
    const float* __restrict__ W,         // 10 x 64 row-major
    const float* __restrict__ gammap, const float* __restrict__ betap,
    const float* __restrict__ rmeanp, const float* __restrict__ rvarp,
    const int* __restrict__ npts_arr,
    const int* __restrict__ coords,      // N x 4: (b, zc, y, x)
    float* __restrict__ pillar_out,      // N*64
    float* __restrict__ bev_vals,        // N*8
    int* __restrict__ winner,            // bs*GY*GX
    int N, int bs)
{
    const int wid  = threadIdx.x >> 6;
    const int lane = threadIdx.x & 63;
    const int half = lane >> 5;
    const int sl   = lane & 31;
    const int n0   = blockIdx.x * 8 + wid * 2;
    const int n    = n0 + half;
    const bool valid = (n < N);
    const int nn = valid ? n : 0;

    // per-channel constants (lane = channel), issued early
    const int d = lane;
    const float w0 = W[d],       w1 = W[64 + d],  w2 = W[128 + d], w3 = W[192 + d];
    const float w4 = W[256 + d], w5 = W[320 + d], w6 = W[384 + d];
    const float w7 = W[448 + d], w8 = W[512 + d], w9 = W[576 + d];
    const float g  = gammap[d], bt = betap[d], rm = rmeanp[d], rv = rvarp[d];

    const int npts = npts_arr[nn];                  // uniform per half
    const int4 crd = ((const int4*)coords)[nn];     // (b, zc, y, x)
    const float cx = (float)crd.w * 0.1f - 51.15f;
    const float cy = (float)crd.z * 0.1f - 51.15f;
    const float cz = (float)crd.y * 4.0f - 1.0f;

    float4 v = make_float4(0.f, 0.f, 0.f, 0.f);
    if (valid) v = vf[(size_t)nn * 32 + sl];        // 64 lanes -> 1KB coalesced
    const bool pv = sl < npts;
    const float m = pv ? 1.f : 0.f;

    // 12 independent DPP reductions (VALU only); results in lanes 31 / 63
    const float sx   = dsum32(v.x);                 // unmasked
    const float sy   = dsum32(v.y);
    const float sz   = dsum32(v.z);
    const float smx  = dsum32(v.x * m);             // masked
    const float smy  = dsum32(v.y * m);
    const float smz  = dsum32(v.z * m);
    const float smI  = dsum32(v.w * m);
    const float sx2  = dsum32(v.x * v.x * m);
    const float sy2  = dsum32(v.y * v.y * m);
    const float sz2  = dsum32(v.z * v.z * m);
    const float maxz = dmax32(pv ? v.z : -1e6f);
    const float minz = dmin32(pv ? v.z :  1e6f);

    // folded per-channel affine: t = px*A + py*B + pz*C + I*D + base
    const float scale = g * rsqrtf(rv + 1e-3f);
    const float shift = fmaf(-rm, scale, bt);       // BN of an all-zero row
    const float A = (w0 + w4 + w7) * scale;
    const float B = (w1 + w5 + w8) * scale;
    const float C = (w2 + w6 + w9) * scale;
    const float D = w3 * scale;

    // channel phase: 64 lanes = 64 channels; points come via v_readlane (SGPR
    // broadcast, no LDS). Loop bound npts is wave-uniform (avg ~16).
#pragma unroll
    for (int h = 0; h < 2; ++h) {
        const int L  = h << 5;
        const int nh = __builtin_amdgcn_readlane(npts, L);
        const float invnh = 1.f / (float)nh;
        const float mx = rdlanef(sx, L + 31) * invnh;
        const float my = rdlanef(sy, L + 31) * invnh;
        const float mz = rdlanef(sz, L + 31) * invnh;
        const float cxh = rdlanef(cx, L), cyh = rdlanef(cy, L), czh = rdlanef(cz, L);
        const float E   = -(mx * w4 + my * w5 + mz * w6 + cxh * w7 + cyh * w8 + czh * w9);
        const float bse = fmaf(E, scale, shift);

        float acc = -1e30f;
        for (int p = 0; p < nh; ++p) {
            const float qx = rdlanef(v.x, L + p);
            const float qy = rdlanef(v.y, L + p);
            const float qz = rdlanef(v.z, L + p);
            const float qw = rdlanef(v.w, L + p);
            acc = fmaxf(acc, fmaf(qx, A, fmaf(qy, B, fmaf(qz, C, fmaf(qw, D, bse)))));
        }
        if (nh < 32) acc = fmaxf(acc, shift);       // masked rows join the max
        acc = fmaxf(acc, 0.f);                      // ReLU commutes with max
        const int np_ = n0 + h;
        if (np_ < N) pillar_out[(size_t)np_ * 64 + lane] = acc;
    }

    // BEV stats: leader lanes 31 / 63 hold their group's reduction results
    if (valid && sl == 31) {
        const float fn = (float)npts, invn = 1.f / fn;
        const float pmx = smx * invn, pmy = smy * invn, pmz = smz * invn;
        const float vvx = fmaf(-pmx, pmx, sx2 * invn);
        const float vvy = fmaf(-pmy, pmy, sy2 * invn);
        const float vvz = fmaf(-pmz, pmz, sz2 * invn);
        float4* bvp = (float4*)&bev_vals[(size_t)n * 8];
        bvp[0] = make_float4(fn * (1.f / 32.f), smI * invn, pmz, maxz);
        bvp[1] = make_float4(maxz - minz, vvx, vvy, vvz);
        const int b = crd.x < 0 ? 0 : (crd.x > bs - 1 ? bs - 1 : crd.x);
        atomicMax(&winner[(b * GYD + crd.z) * GXD + crd.w], n + 1);  // last-write-wins
    }
}

// One thread per FOUR BEV cells: writes all of vox_bev exactly once.
__global__ __launch_bounds__(256) void bev_fill(
    const int4* __restrict__ winner4,
    const float* __restrict__ bev_vals,
    float* __restrict__ vox_bev, int bs)
{
    const int gidx = blockIdx.x * 256 + threadIdx.x;   // < (bs<<20)/4
    const int4 w = winner4[gidx];
    const int c0 = gidx << 2;
    const int b  = c0 >> 20;                           // GY*GX = 1<<20
    const int yx = c0 & ((1 << 20) - 1);
    float* basep = vox_bev + (((size_t)b * NUM_BEV) << 20) + yx;
    if ((w.x | w.y | w.z | w.w) == 0) {                // common path (~98% of cells)
        const float4 z4 = make_float4(0.f, 0.f, 0.f, 0.f);
#pragma unroll
        for (int k = 0; k < NUM_BEV; ++k)
            *(float4*)(basep + ((size_t)k << 20)) = z4;
    } else {
#pragma unroll
        for (int k = 0; k < NUM_BEV; ++k) {
            float4 o;
            o.x = (w.x > 0) ? bev_vals[(size_t)(w.x - 1) * 8 + k] : 0.f;
            o.y = (w.y > 0) ? bev_vals[(size_t)(w.y - 1) * 8 + k] : 0.f;
            o.z = (w.z > 0) ? bev_vals[(size_t)(w.z - 1) * 8 + k] : 0.f;
            o.w = (w.w > 0) ? bev_vals[(size_t)(w.w - 1) * 8 + k] : 0.f;
            *(float4*)(basep + ((size_t)k << 20)) = o;
        }
    }
}

extern "C" void kernel_launch(void* const* d_in, const int* in_sizes, int n_in,
                              void* d_out, int out_size, void* d_ws, size_t ws_size,
                              hipStream_t stream) {
    const float4* vf    = (const float4*)d_in[0];
    const float* W      = (const float*)d_in[1];
    const float* gammap = (const float*)d_in[2];
    const float* betap  = (const float*)d_in[3];
    const float* rmeanp = (const float*)d_in[4];
    const float* rvarp  = (const float*)d_in[5];
    const int* npts     = (const int*)d_in[6];
    const int* coords   = (const int*)d_in[7];
    const int N  = in_sizes[6];
    const int bs = in_sizes[8];

    float* pillar_out = (float*)d_out;                   // N*64
    float* vox_bev    = (float*)d_out + (size_t)N * 64;  // bs*8*GY*GX

    int* winner     = (int*)d_ws;                        // bs*GY*GX ints
    float* bev_vals = (float*)((char*)d_ws + (size_t)bs * GYD * GXD * sizeof(int));

    hipMemsetAsync(winner, 0, (size_t)bs * GYD * GXD * sizeof(int), stream);

    const int blocksA = (N + 7) / 8;                     // 8 pillars per block
    pillar_kernel<<<blocksA, 256, 0, stream>>>(vf, W, gammap, betap, rmeanp, rvarp,
                                               npts, coords, pillar_out, bev_vals,
                                               winner, N, bs);
    const int blocksB = (bs << 20) / (256 * 4);          // 4 cells per thread
    bev_fill<<<blocksB, 256, 0, stream>>>((const int4*)winner, bev_vals, vox_bev, bs);
}

// Round 5
// 130.541 us; speedup vs baseline: 1.0916x; 1.0916x over previous
//
#include <hip/hip_runtime.h>

#define GYD 1024
#define GXD 1024
#define NUM_BEV 8

__device__ __forceinline__ float rdlanef(float x, int l) {
    return __int_as_float(__builtin_amdgcn_readlane(__float_as_int(x), l));
}
template <int CTRL, int ROWMASK>
__device__ __forceinline__ float dppf(float x, float oldv) {
    return __int_as_float(__builtin_amdgcn_update_dpp(
        __float_as_int(oldv), __float_as_int(x), CTRL, ROWMASK, 0xF, false));
}
// 32-lane-group reductions, pure VALU. Group result lands in lanes 31 / 63.
__device__ __forceinline__ float dsum32(float x) {
    x += dppf<0x111, 0xF>(x, 0.f);   // row_shr:1
    x += dppf<0x112, 0xF>(x, 0.f);   // row_shr:2
    x += dppf<0x114, 0xF>(x, 0.f);   // row_shr:4
    x += dppf<0x118, 0xF>(x, 0.f);   // row_shr:8
    x += dppf<0x142, 0xA>(x, 0.f);   // row_bcast:15 into rows 1,3
    return x;
}
__device__ __forceinline__ float dmax32(float x) {
    x = fmaxf(x, dppf<0x111, 0xF>(x, x));
    x = fmaxf(x, dppf<0x112, 0xF>(x, x));
    x = fmaxf(x, dppf<0x114, 0xF>(x, x));
    x = fmaxf(x, dppf<0x118, 0xF>(x, x));
    x = fmaxf(x, dppf<0x142, 0xA>(x, x));
    return x;
}
__device__ __forceinline__ float dmin32(float x) {
    x = fminf(x, dppf<0x111, 0xF>(x, x));
    x = fminf(x, dppf<0x112, 0xF>(x, x));
    x = fminf(x, dppf<0x114, 0xF>(x, x));
    x = fminf(x, dppf<0x118, 0xF>(x, x));
    x = fminf(x, dppf<0x142, 0xA>(x, x));
    return x;
}

// float2 helpers (packed-fp32 candidates: v_pk_fma_f32 / v_pk_add_f32)
__device__ __forceinline__ float2 f2(float a)            { return make_float2(a, a); }
__device__ __forceinline__ float2 add2(float2 a, float2 b){ return make_float2(a.x+b.x, a.y+b.y); }
__device__ __forceinline__ float2 mul2(float2 a, float2 b){ return make_float2(a.x*b.x, a.y*b.y); }
__device__ __forceinline__ float2 fma2(float2 a, float2 b, float2 c){
    return make_float2(fmaf(a.x,b.x,c.x), fmaf(a.y,b.y,c.y));
}
__device__ __forceinline__ float2 max2(float2 a, float2 b){
    return make_float2(fmaxf(a.x,b.x), fmaxf(a.y,b.y));
}

// TWO pillars per wave: lanes 0-31 = pillar A's points, 32-63 = pillar B's.
// Channel phase: lane sl handles channels sl and sl+32 of its half's pillar.
__global__ __launch_bounds__(256) void pillar_kernel(
    const float4* __restrict__ vf,       // N*32 points (x,y,z,intensity)
    const float* __restrict__ W,         // 10 x 64 row-major
    const float* __restrict__ gammap, const float* __restrict__ betap,
    const float* __restrict__ rmeanp, const float* __restrict__ rvarp,
    const int* __restrict__ npts_arr,
    const int* __restrict__ coords,      // N x 4: (b, zc, y, x)
    float* __restrict__ pillar_out,      // N*64
    float* __restrict__ bev_vals,        // N*8
    int* __restrict__ winner,            // bs*GY*GX
    int N, int bs)
{
    __shared__ float4 pts[4][2][32];
    const int wid  = threadIdx.x >> 6;
    const int lane = threadIdx.x & 63;
    const int half = lane >> 5;
    const int sl   = lane & 31;
    const int n0   = blockIdx.x * 8 + wid * 2;
    const int n    = n0 + half;
    const bool valid = (n < N);
    const int nn = valid ? n : 0;

    // channel-pair constants: lane sl covers channels sl and sl+32
    const int c0 = sl, c1 = sl + 32;
    float2 w_[10];
#pragma unroll
    for (int k = 0; k < 10; ++k)
        w_[k] = make_float2(W[k * 64 + c0], W[k * 64 + c1]);
    const float2 gg = make_float2(gammap[c0], gammap[c1]);
    const float2 bb = make_float2(betap[c0],  betap[c1]);
    const float2 rmn= make_float2(rmeanp[c0], rmeanp[c1]);
    const float2 rvr= make_float2(rvarp[c0],  rvarp[c1]);

    const int npts = npts_arr[nn];                  // own pillar (uniform per half)
    const int4 crd = ((const int4*)coords)[nn];     // (b, zc, y, x)
    const float cx = (float)crd.w * 0.1f - 51.15f;
    const float cy = (float)crd.z * 0.1f - 51.15f;
    const float cz = (float)crd.y * 4.0f - 1.0f;

    float4 v = make_float4(0.f, 0.f, 0.f, 0.f);
    if (valid) v = vf[(size_t)nn * 32 + sl];        // coalesced 1KB/wave
    const bool pv = sl < npts;
    const float m = pv ? 1.f : 0.f;

    // stage points; pad invalid slots with point 0 (max-neutral duplicate)
    pts[wid][half][sl] = v;
    const float4 p0 = pts[wid][half][0];            // same-wave LDS, compiler waits
    if (!pv) pts[wid][half][sl] = p0;

    // 12 shared DPP reductions; results in lanes 31 (A) / 63 (B)
    const float sx   = dsum32(v.x);                 // unmasked
    const float sy   = dsum32(v.y);
    const float sz   = dsum32(v.z);
    const float smx  = dsum32(v.x * m);             // masked
    const float smy  = dsum32(v.y * m);
    const float smz  = dsum32(v.z * m);
    const float smI  = dsum32(v.w * m);
    const float sx2  = dsum32(v.x * v.x * m);
    const float sy2  = dsum32(v.y * v.y * m);
    const float sz2  = dsum32(v.z * v.z * m);
    const float maxz = dmax32(pv ? v.z : -1e6f);
    const float minz = dmin32(pv ? v.z :  1e6f);

    // distribute unmasked means to all lanes of the owning half
    const float invn = 1.f / (float)npts;
    const float mx = (half ? rdlanef(sx, 63) : rdlanef(sx, 31)) * invn;
    const float my = (half ? rdlanef(sy, 63) : rdlanef(sy, 31)) * invn;
    const float mz = (half ? rdlanef(sz, 63) : rdlanef(sz, 31)) * invn;

    // wave-uniform loop bound
    const int nA = __builtin_amdgcn_readlane(npts, 0);
    const int nB = __builtin_amdgcn_readlane(npts, 32);
    const int nmax = nA > nB ? nA : nB;

    // folded BN+affine per channel pair
    const float2 scale = mul2(gg, make_float2(rsqrtf(rvr.x + 1e-3f), rsqrtf(rvr.y + 1e-3f)));
    const float2 shift = fma2(f2(-1.f), mul2(rmn, scale), bb);   // bb - rmn*scale
    const float2 A = mul2(add2(add2(w_[0], w_[4]), w_[7]), scale);
    const float2 B = mul2(add2(add2(w_[1], w_[5]), w_[8]), scale);
    const float2 C = mul2(add2(add2(w_[2], w_[6]), w_[9]), scale);
    const float2 D = mul2(w_[3], scale);
    float2 E = mul2(f2(mx), w_[4]);
    E = fma2(f2(my), w_[5], E);
    E = fma2(f2(mz), w_[6], E);
    E = fma2(f2(cx), w_[7], E);
    E = fma2(f2(cy), w_[8], E);
    E = fma2(f2(cz), w_[9], E);
    const float2 bse = fma2(f2(-1.f), mul2(E, scale), shift);    // shift - E*scale

    float2 acc = make_float2(-1e30f, -1e30f);
#pragma unroll 2
    for (int p = 0; p < nmax; ++p) {
        const float4 q = pts[wid][half][p];          // 2 addrs/wave: free 2-way
        const float2 t = fma2(f2(q.x), A, fma2(f2(q.y), B,
                         fma2(f2(q.z), C, fma2(f2(q.w), D, bse))));
        acc = max2(acc, t);
    }
    if (npts < 32) acc = max2(acc, shift);           // masked rows join the max
    acc = max2(acc, f2(0.f));                        // ReLU commutes with max

    if (valid) {
        pillar_out[(size_t)n * 64 + c0] = acc.x;
        pillar_out[(size_t)n * 64 + c1] = acc.y;
    }

    // BEV stats: lanes 31 / 63 already hold their group's reduction results
    if (valid && sl == 31) {
        const float fn = (float)npts;
        const float pmx = smx * invn, pmy = smy * invn, pmz = smz * invn;
        const float vvx = fmaf(-pmx, pmx, sx2 * invn);
        const float vvy = fmaf(-pmy, pmy, sy2 * invn);
        const float vvz = fmaf(-pmz, pmz, sz2 * invn);
        float4* bvp = (float4*)&bev_vals[(size_t)n * 8];
        bvp[0] = make_float4(fn * (1.f / 32.f), smI * invn, pmz, maxz);
        bvp[1] = make_float4(maxz - minz, vvx, vvy, vvz);
        const int b = crd.x < 0 ? 0 : (crd.x > bs - 1 ? bs - 1 : crd.x);
        atomicMax(&winner[(b * GYD + crd.z) * GXD + crd.w], n + 1);  // last-write-wins
    }
}

// One thread per FOUR BEV cells: writes all of vox_bev exactly once.
__global__ __launch_bounds__(256) void bev_fill(
    const int4* __restrict__ winner4,
    const float* __restrict__ bev_vals,
    float* __restrict__ vox_bev, int bs)
{
    const int gidx = blockIdx.x * 256 + threadIdx.x;   // < (bs<<20)/4
    const int4 w = winner4[gidx];
    const int c0 = gidx << 2;
    const int b  = c0 >> 20;                           // GY*GX = 1<<20
    const int yx = c0 & ((1 << 20) - 1);
    float* basep = vox_bev + (((size_t)b * NUM_BEV) << 20) + yx;
    if ((w.x | w.y | w.z | w.w) == 0) {                // ~92% of threads
        const float4 z4 = make_float4(0.f, 0.f, 0.f, 0.f);
#pragma unroll
        for (int k = 0; k < NUM_BEV; ++k)
            *(float4*)(basep + ((size_t)k << 20)) = z4;
    } else {
#pragma unroll
        for (int k = 0; k < NUM_BEV; ++k) {
            float4 o;
            o.x = (w.x > 0) ? bev_vals[(size_t)(w.x - 1) * 8 + k] : 0.f;
            o.y = (w.y > 0) ? bev_vals[(size_t)(w.y - 1) * 8 + k] : 0.f;
            o.z = (w.z > 0) ? bev_vals[(size_t)(w.z - 1) * 8 + k] : 0.f;
            o.w = (w.w > 0) ? bev_vals[(size_t)(w.w - 1) * 8 + k] : 0.f;
            *(float4*)(basep + ((size_t)k << 20)) = o;
        }
    }
}

extern "C" void kernel_launch(void* const* d_in, const int* in_sizes, int n_in,
                              void* d_out, int out_size, void* d_ws, size_t ws_size,
                              hipStream_t stream) {
    const float4* vf    = (const float4*)d_in[0];
    const float* W      = (const float*)d_in[1];
    const float* gammap = (const float*)d_in[2];
    const float* betap  = (const float*)d_in[3];
    const float* rmeanp = (const float*)d_in[4];
    const float* rvarp  = (const float*)d_in[5];
    const int* npts     = (const int*)d_in[6];
    const int* coords   = (const int*)d_in[7];
    const int N  = in_sizes[6];
    const int bs = in_sizes[8];

    float* pillar_out = (float*)d_out;                   // N*64
    float* vox_bev    = (float*)d_out + (size_t)N * 64;  // bs*8*GY*GX

    int* winner     = (int*)d_ws;                        // bs*GY*GX ints
    float* bev_vals = (float*)((char*)d_ws + (size_t)bs * GYD * GXD * sizeof(int));

    hipMemsetAsync(winner, 0, (size_t)bs * GYD * GXD * sizeof(int), stream);

    const int blocksA = (N + 7) / 8;                     // 8 pillars per block
    pillar_kernel<<<blocksA, 256, 0, stream>>>(vf, W, gammap, betap, rmeanp, rvarp,
                                               npts, coords, pillar_out, bev_vals,
                                               winner, N, bs);
    const int blocksB = (bs << 20) / (256 * 4);          // 4 cells per thread
    bev_fill<<<blocksB, 256, 0, stream>>>((const int4*)winner, bev_vals, vox_bev, bs);
}